// Round 15
// baseline (110.359 us; speedup 1.0000x reference)
//
#include <hip/hip_runtime.h>
#include <cfloat>
#include <math.h>

#define D_IN 128
#define D_OUT 64
#define NEG_SLOPE 0.2f
#define ROWH 128  // ushorts per hkv row: [64 fp16 k | 64 fp16 v] = 256 B
#define SQRT_LOG2E 1.2011224087864498f
#define DEFER_THR 8.0f

typedef _Float16 half2v __attribute__((ext_vector_type(2)));
typedef _Float16 half8 __attribute__((ext_vector_type(8)));
typedef float f32x4 __attribute__((ext_vector_type(4)));

// helpers ---------------------------------------------------------------------
__device__ __forceinline__ unsigned short f2h(float x) {
  union { _Float16 h; unsigned short u; } c;
  c.h = (_Float16)x;  // RNE
  return c.u;
}
__device__ __forceinline__ float hdot2(unsigned a, unsigned b, float c) {
  union { unsigned u; half2v h; } x, y;
  x.u = a; y.u = b;
#if __has_builtin(__builtin_amdgcn_fdot2)
  return __builtin_amdgcn_fdot2(x.h, y.h, c, false);
#else
  return c + (float)x.h[0] * (float)y.h[0] + (float)x.h[1] * (float)y.h[1];
#endif
}

// ---------------------------------------------------------------------------
// Kernel P: pack W (f32) into per-lane MFMA B-fragments (fp16).
// Wk pre-scaled by sqrt(log2 e) so gathered score dots land in exp2 domain.
// ---------------------------------------------------------------------------
__global__ void bfrag_kernel(const float* __restrict__ Wk,
                             const float* __restrict__ Wv,
                             _Float16* __restrict__ bfrag) {
  const int idx = blockIdx.x * 256 + threadIdx.x;
  if (idx >= 2048) return;
  const int which = idx >> 10;
  const float* __restrict__ W = which ? Wv : Wk;
  const float scale = which ? 1.0f : SQRT_LOG2E;
  const int li = idx & 1023;
  const int lane = li & 63;
  const int nt = (li >> 6) & 3;
  const int k0i = li >> 8;
  const int col = nt * 16 + (lane & 15);
  const int kbase = k0i * 32 + (lane >> 4) * 8;
  half8 h;
#pragma unroll
  for (int j = 0; j < 8; ++j)
    h[j] = (_Float16)(W[(size_t)(kbase + j) * D_OUT + col] * scale);
  reinterpret_cast<half8*>(bfrag)[idx] = h;
}

// ---------------------------------------------------------------------------
// Kernel A: H = X @ W + b via mfma_f32_16x16x32_f16 (unchanged from R11).
// which==0 -> fp16 k at ushort col (pre-scaled); which==1 -> fp16 v at 64+col.
// ---------------------------------------------------------------------------
__global__ __launch_bounds__(256) void linear_mfma_kernel(
    const float* __restrict__ Xk, const float* __restrict__ Xv,
    const float* __restrict__ Wk, const float* __restrict__ bk,
    const float* __restrict__ Wv, const float* __restrict__ bv,
    const _Float16* __restrict__ bfrag, unsigned short* __restrict__ hkv,
    int R, int nblk) {
  const int which = (blockIdx.x >= nblk) ? 1 : 0;
  const int blk = blockIdx.x - which * nblk;
  const float* __restrict__ X = which ? Xv : Xk;
  const float* __restrict__ bias = which ? bv : bk;
  const float bscale = which ? 1.0f : SQRT_LOG2E;
  const int uoff = which ? D_OUT : 0;

  const int wave = threadIdx.x >> 6;
  const int lane = threadIdx.x & 63;
  const int r0 = (blk * 4 + wave) * 16;
  if (r0 >= R) return;
  const int rowi = lane & 15;
  const int kgrp = lane >> 4;

  if (r0 + 16 <= R) {
    const half8* btab =
        reinterpret_cast<const half8*>(bfrag) + (which ? 1024 : 0);
    half8 bf[4][4];
#pragma unroll
    for (int k0i = 0; k0i < 4; ++k0i)
#pragma unroll
      for (int nt = 0; nt < 4; ++nt)
        bf[k0i][nt] = btab[(k0i * 4 + nt) * 64 + lane];

    f32x4 acc[4];
#pragma unroll
    for (int nt = 0; nt < 4; ++nt) acc[nt] = (f32x4){0.f, 0.f, 0.f, 0.f};

    const float* xrow = X + (size_t)(r0 + rowi) * D_IN;
#pragma unroll
    for (int k0i = 0; k0i < 4; ++k0i) {
      const float4 x0 =
          *reinterpret_cast<const float4*>(xrow + k0i * 32 + kgrp * 8);
      const float4 x1 =
          *reinterpret_cast<const float4*>(xrow + k0i * 32 + kgrp * 8 + 4);
      half8 a;
      a[0] = (_Float16)x0.x; a[1] = (_Float16)x0.y;
      a[2] = (_Float16)x0.z; a[3] = (_Float16)x0.w;
      a[4] = (_Float16)x1.x; a[5] = (_Float16)x1.y;
      a[6] = (_Float16)x1.z; a[7] = (_Float16)x1.w;
#pragma unroll
      for (int nt = 0; nt < 4; ++nt)
        acc[nt] = __builtin_amdgcn_mfma_f32_16x16x32_f16(a, bf[k0i][nt],
                                                         acc[nt], 0, 0, 0);
    }
#pragma unroll
    for (int nt = 0; nt < 4; ++nt) {
      const int col = nt * 16 + rowi;
      const float bcol = bias[col] * bscale;
#pragma unroll
      for (int r = 0; r < 4; ++r) {
        const int row = r0 + kgrp * 4 + r;
        hkv[(size_t)row * ROWH + uoff + col] = f2h(acc[nt][r] + bcol);
      }
    }
  } else {
    const float* __restrict__ W = which ? Wv : Wk;
    for (int r = r0; r < R; ++r) {
      const float* xr = X + (size_t)r * D_IN;
      float acc = bias[lane];
      for (int k = 0; k < D_IN; ++k)
        acc = fmaf(xr[k], W[(size_t)k * D_OUT + lane], acc);
      acc *= bscale;
      hkv[(size_t)r * ROWH + uoff + lane] = f2h(acc);
    }
  }
}

// ---------------------------------------------------------------------------
// Kernel B: CSR row pointers from sorted dst.
// ---------------------------------------------------------------------------
__global__ void rowptr_kernel(const int* __restrict__ dst, int E, int N,
                              int* __restrict__ row_ptr) {
  int i = blockIdx.x * blockDim.x + threadIdx.x;
  if (i > N) return;
  int lo = 0, hi = E;
  while (lo < hi) {
    int mid = (lo + hi) >> 1;
    if (dst[mid] < i) lo = mid + 1; else hi = mid;
  }
  row_ptr[i] = lo;
}

// ---------------------------------------------------------------------------
// Aggregate: 8-lane groups. Lane owns 8 dims (16 B). Wave = 1 node x
// {4 edge-slots (w) x 2 batches}. 4 ILP chains per group (A-D, stride 16)
// keep 8 gather loads in flight. Batch folded into per-lane base offset.
// ---------------------------------------------------------------------------
struct SMState { float m, l; float4 a0, a1; };

__device__ __forceinline__ void sm_update(SMState& st, float pl,
                                          const uint4& vq) {
  if (pl > st.m + DEFER_THR) {  // rare
    const float sc = exp2f(st.m - pl);  // first edge: exp2(-inf) = 0
    st.l *= sc;
    st.a0.x *= sc; st.a0.y *= sc; st.a0.z *= sc; st.a0.w *= sc;
    st.a1.x *= sc; st.a1.y *= sc; st.a1.z *= sc; st.a1.w *= sc;
    st.m = pl;
  }
  const float a = exp2f(pl - st.m);
  st.l += a;
  union { unsigned u; half2v h; } c;
  c.u = vq.x;
  st.a0.x = fmaf(a, (float)c.h[0], st.a0.x);
  st.a0.y = fmaf(a, (float)c.h[1], st.a0.y);
  c.u = vq.y;
  st.a0.z = fmaf(a, (float)c.h[0], st.a0.z);
  st.a0.w = fmaf(a, (float)c.h[1], st.a0.w);
  c.u = vq.z;
  st.a1.x = fmaf(a, (float)c.h[0], st.a1.x);
  st.a1.y = fmaf(a, (float)c.h[1], st.a1.y);
  c.u = vq.w;
  st.a1.z = fmaf(a, (float)c.h[0], st.a1.z);
  st.a1.w = fmaf(a, (float)c.h[1], st.a1.w);
}

__device__ __forceinline__ void sm_merge(SMState& d, const SMState& s) {
  const float mn = fmaxf(d.m, s.m);
  const float s1 = exp2f(d.m - mn);
  const float s2 = exp2f(s.m - mn);
  d.l = d.l * s1 + s.l * s2;
  d.a0.x = d.a0.x * s1 + s.a0.x * s2;
  d.a0.y = d.a0.y * s1 + s.a0.y * s2;
  d.a0.z = d.a0.z * s1 + s.a0.z * s2;
  d.a0.w = d.a0.w * s1 + s.a0.w * s2;
  d.a1.x = d.a1.x * s1 + s.a1.x * s2;
  d.a1.y = d.a1.y * s1 + s.a1.y * s2;
  d.a1.z = d.a1.z * s1 + s.a1.z * s2;
  d.a1.w = d.a1.w * s1 + s.a1.w * s2;
  d.m = mn;
}

__device__ __forceinline__ void sm_merge_shfl(SMState& d, int off) {
  SMState s;
  s.m = __shfl_xor(d.m, off, 64);
  s.l = __shfl_xor(d.l, off, 64);
  s.a0.x = __shfl_xor(d.a0.x, off, 64);
  s.a0.y = __shfl_xor(d.a0.y, off, 64);
  s.a0.z = __shfl_xor(d.a0.z, off, 64);
  s.a0.w = __shfl_xor(d.a0.w, off, 64);
  s.a1.x = __shfl_xor(d.a1.x, off, 64);
  s.a1.y = __shfl_xor(d.a1.y, off, 64);
  s.a1.z = __shfl_xor(d.a1.z, off, 64);
  s.a1.w = __shfl_xor(d.a1.w, off, 64);
  sm_merge(d, s);
}

// one edge-visit: k uint4 + v uint4 (independent), 8-dim dot, 3-step reduce
__device__ __forceinline__ void edge_proc(const char* __restrict__ hbase,
                                          unsigned off, const uint4& kd,
                                          SMState& st) {
  const uint4 kq = *reinterpret_cast<const uint4*>(hbase + off);
  const uint4 vq = *reinterpret_cast<const uint4*>(hbase + off + 128);
  float p = hdot2(kq.x, kd.x, 0.f);
  p = hdot2(kq.y, kd.y, p);
  p = hdot2(kq.z, kd.z, p);
  p = hdot2(kq.w, kd.w, p);
  p += __shfl_xor(p, 1, 64);
  p += __shfl_xor(p, 2, 64);
  p += __shfl_xor(p, 4, 64);
  sm_update(st, p, vq);
}

__global__ __launch_bounds__(256) void aggregate_kernel(
    const unsigned short* __restrict__ hkv, const int* __restrict__ src,
    const int* __restrict__ row_ptr, float* __restrict__ out, int N) {
  const int node = blockIdx.x * 4 + (threadIdx.x >> 6);
  const int lane = threadIdx.x & 63;
  if (node >= N) return;
  const char* hbase = reinterpret_cast<const char*>(hkv);

  const int li = lane & 7;          // dim-octet index (16 B)
  const int w = (lane >> 3) & 3;    // edge slot
  const int batch = lane >> 5;
  // per-lane constant base offset: batch row block + dim offset
  const unsigned bo = (unsigned)batch * ((unsigned)N * 256u) + (unsigned)li * 16u;

  const uint4 kd =
      *reinterpret_cast<const uint4*>(hbase + ((unsigned)node << 8) + bo);
  const int e0 = row_ptr[node];
  const int e1 = row_ptr[node + 1];

  SMState A = {-FLT_MAX, 0.f, {0, 0, 0, 0}, {0, 0, 0, 0}};
  SMState B = A, C = A, D = A;

  int e = e0 + w;
  for (; e + 12 < e1; e += 16) {
    const unsigned oA = ((unsigned)src[e] << 8) + bo;
    const unsigned oB = ((unsigned)src[e + 4] << 8) + bo;
    const unsigned oC = ((unsigned)src[e + 8] << 8) + bo;
    const unsigned oD = ((unsigned)src[e + 12] << 8) + bo;
    edge_proc(hbase, oA, kd, A);
    edge_proc(hbase, oB, kd, B);
    edge_proc(hbase, oC, kd, C);
    edge_proc(hbase, oD, kd, D);
  }
  // tail: up to 3 remaining stride-4 edges for this slot
  for (; e < e1; e += 4) {
    const unsigned oA = ((unsigned)src[e] << 8) + bo;
    edge_proc(hbase, oA, kd, A);
  }

  sm_merge(A, B);
  sm_merge(C, D);
  sm_merge(A, C);
  sm_merge_shfl(A, 8);   // merge edge slots w^1
  sm_merge_shfl(A, 16);  // merge edge slots w^2
  // lanes with w==0 (0-7 batch0, 32-39 batch1) hold the full state

  if (w == 0) {
    const float denom = (A.l == 0.f) ? 1.f : A.l;
    const float inv = 1.f / denom;
    float4 o0, o1;
    o0.x = A.a0.x * inv; o0.y = A.a0.y * inv;
    o0.z = A.a0.z * inv; o0.w = A.a0.w * inv;
    o1.x = A.a1.x * inv; o1.y = A.a1.y * inv;
    o1.z = A.a1.z * inv; o1.w = A.a1.w * inv;
    o0.x = (o0.x >= 0.f) ? o0.x : NEG_SLOPE * o0.x;
    o0.y = (o0.y >= 0.f) ? o0.y : NEG_SLOPE * o0.y;
    o0.z = (o0.z >= 0.f) ? o0.z : NEG_SLOPE * o0.z;
    o0.w = (o0.w >= 0.f) ? o0.w : NEG_SLOPE * o0.w;
    o1.x = (o1.x >= 0.f) ? o1.x : NEG_SLOPE * o1.x;
    o1.y = (o1.y >= 0.f) ? o1.y : NEG_SLOPE * o1.y;
    o1.z = (o1.z >= 0.f) ? o1.z : NEG_SLOPE * o1.z;
    o1.w = (o1.w >= 0.f) ? o1.w : NEG_SLOPE * o1.w;
    float* orow = out + ((size_t)batch * N + node) * D_OUT + li * 8;
    reinterpret_cast<float4*>(orow)[0] = o0;
    reinterpret_cast<float4*>(orow)[1] = o1;
  }
}

// ---------------------------------------------------------------------------
extern "C" void kernel_launch(void* const* d_in, const int* in_sizes, int n_in,
                              void* d_out, int out_size, void* d_ws,
                              size_t ws_size, hipStream_t stream) {
  const float* X_key   = (const float*)d_in[0];
  const float* X_value = (const float*)d_in[1];
  const float* Wk      = (const float*)d_in[2];
  const float* bk      = (const float*)d_in[3];
  const float* Wv      = (const float*)d_in[4];
  const float* bv      = (const float*)d_in[5];
  const int*   src     = (const int*)d_in[6];
  const int*   dst     = (const int*)d_in[7];
  float* out = (float*)d_out;

  const int B = 2;
  const int R = in_sizes[0] / D_IN;  // B*N rows
  const int N = R / B;
  const int E = in_sizes[6];

  // workspace: bfrag 32KB (16B-aligned) | hkv ushort[R][128] | row_ptr
  _Float16* bfrag = (_Float16*)d_ws;
  unsigned short* hkv = (unsigned short*)((char*)d_ws + 32768);
  int* row_ptr = (int*)(hkv + (size_t)R * ROWH);

  const int blocksB = (N + 1 + 255) / 256;
  hipLaunchKernelGGL(rowptr_kernel, dim3(blocksB), dim3(256), 0, stream,
                     dst, E, N, row_ptr);
  hipLaunchKernelGGL(bfrag_kernel, dim3(8), dim3(256), 0, stream,
                     Wk, Wv, bfrag);
  const int wavesPerMat = (R + 15) / 16;
  const int nblk = (wavesPerMat + 3) / 4;
  hipLaunchKernelGGL(linear_mfma_kernel, dim3(2 * nblk), dim3(256), 0, stream,
                     X_key, X_value, Wk, bk, Wv, bv, bfrag, hkv, R, nblk);
  const int blocksC = (N + 3) / 4;  // one wave per node, both batches
  hipLaunchKernelGGL(aggregate_kernel, dim3(blocksC), dim3(256), 0, stream,
                     hkv, src, row_ptr, out, N);
}

// Round 16
// 100.171 us; speedup vs baseline: 1.1017x; 1.1017x over previous
//
#include <hip/hip_runtime.h>
#include <cfloat>
#include <math.h>

#define D_IN 128
#define D_OUT 64
#define NEG_SLOPE 0.2f
#define ROWH 128  // ushorts per hkv row: 64 fp16 (hk) + 64 bf16 (hv) = 256 B
#define SQRT_LOG2E 1.2011224087864498f

typedef _Float16 half2v __attribute__((ext_vector_type(2)));
typedef _Float16 half8 __attribute__((ext_vector_type(8)));
typedef float f32x4 __attribute__((ext_vector_type(4)));

// pack/unpack helpers ---------------------------------------------------------
__device__ __forceinline__ unsigned short f2bf(float x) {
  union { float f; unsigned u; } a; a.f = x;
  unsigned r = a.u + 0x7FFFu + ((a.u >> 16) & 1u);
  return (unsigned short)(r >> 16);
}
__device__ __forceinline__ unsigned short f2h(float x) {
  union { _Float16 h; unsigned short u; } c;
  c.h = (_Float16)x;  // RNE
  return c.u;
}
__device__ __forceinline__ float4 unpack_bf4(uint2 q) {
  union { unsigned u; float f; } t;
  float4 r;
  t.u = q.x << 16;          r.x = t.f;
  t.u = q.x & 0xFFFF0000u;  r.y = t.f;
  t.u = q.y << 16;          r.z = t.f;
  t.u = q.y & 0xFFFF0000u;  r.w = t.f;
  return r;
}
// fp16-pair dot with f32 accumulate via v_dot2_f32_f16
__device__ __forceinline__ float hdot4(uint2 a, uint2 b) {
  union { unsigned u; half2v h; } al, ah, bl, bh;
  al.u = a.x; ah.u = a.y; bl.u = b.x; bh.u = b.y;
#if __has_builtin(__builtin_amdgcn_fdot2)
  return __builtin_amdgcn_fdot2(al.h, bl.h,
         __builtin_amdgcn_fdot2(ah.h, bh.h, 0.f, false), false);
#else
  return (float)al.h[0] * (float)bl.h[0] + (float)al.h[1] * (float)bl.h[1] +
         (float)ah.h[0] * (float)bh.h[0] + (float)ah.h[1] * (float)bh.h[1];
#endif
}

// ---------------------------------------------------------------------------
// Kernel P: pack W (f32) into per-lane MFMA B-fragments (fp16).
// Wk pre-scaled by sqrt(log2 e) so gathered score dots land in exp2 domain.
// idx < 1024: Wk table; idx >= 1024: Wv table. 2048 entries x 16 B = 32 KB.
// ---------------------------------------------------------------------------
__global__ void bfrag_kernel(const float* __restrict__ Wk,
                             const float* __restrict__ Wv,
                             _Float16* __restrict__ bfrag) {
  const int idx = blockIdx.x * 256 + threadIdx.x;
  if (idx >= 2048) return;
  const int which = idx >> 10;
  const float* __restrict__ W = which ? Wv : Wk;
  const float scale = which ? 1.0f : SQRT_LOG2E;
  const int li = idx & 1023;
  const int lane = li & 63;
  const int nt = (li >> 6) & 3;
  const int k0i = li >> 8;
  const int col = nt * 16 + (lane & 15);
  const int kbase = k0i * 32 + (lane >> 4) * 8;
  half8 h;
#pragma unroll
  for (int j = 0; j < 8; ++j)
    h[j] = (_Float16)(W[(size_t)(kbase + j) * D_OUT + col] * scale);
  reinterpret_cast<half8*>(bfrag)[idx] = h;
}

// ---------------------------------------------------------------------------
// Kernel A: H = X @ W + b via mfma_f32_16x16x32_f16.
// One wave = 16 rows x 64 cols (4 col-tiles x 4 K-steps = 16 MFMAs).
// C/D: col = lane&15 (+nt*16), row = r0 + (lane>>4)*4 + r   [m89 mapping]
// which==0 -> fp16 hk (pre-scaled by sqrt(log2e)); which==1 -> bf16 hv.
// ---------------------------------------------------------------------------
__global__ __launch_bounds__(256) void linear_mfma_kernel(
    const float* __restrict__ Xk, const float* __restrict__ Xv,
    const float* __restrict__ Wk, const float* __restrict__ bk,
    const float* __restrict__ Wv, const float* __restrict__ bv,
    const _Float16* __restrict__ bfrag, unsigned short* __restrict__ hkv,
    int R, int nblk) {
  const int which = (blockIdx.x >= nblk) ? 1 : 0;
  const int blk = blockIdx.x - which * nblk;
  const float* __restrict__ X = which ? Xv : Xk;
  const float* __restrict__ bias = which ? bv : bk;
  const float bscale = which ? 1.0f : SQRT_LOG2E;
  const int uoff = which ? D_OUT : 0;

  const int wave = threadIdx.x >> 6;
  const int lane = threadIdx.x & 63;
  const int r0 = (blk * 4 + wave) * 16;
  if (r0 >= R) return;
  const int rowi = lane & 15;
  const int kgrp = lane >> 4;

  if (r0 + 16 <= R) {
    const half8* btab =
        reinterpret_cast<const half8*>(bfrag) + (which ? 1024 : 0);
    half8 bf[4][4];
#pragma unroll
    for (int k0i = 0; k0i < 4; ++k0i)
#pragma unroll
      for (int nt = 0; nt < 4; ++nt)
        bf[k0i][nt] = btab[(k0i * 4 + nt) * 64 + lane];

    f32x4 acc[4];
#pragma unroll
    for (int nt = 0; nt < 4; ++nt) acc[nt] = (f32x4){0.f, 0.f, 0.f, 0.f};

    const float* xrow = X + (size_t)(r0 + rowi) * D_IN;
#pragma unroll
    for (int k0i = 0; k0i < 4; ++k0i) {
      const float4 x0 =
          *reinterpret_cast<const float4*>(xrow + k0i * 32 + kgrp * 8);
      const float4 x1 =
          *reinterpret_cast<const float4*>(xrow + k0i * 32 + kgrp * 8 + 4);
      half8 a;
      a[0] = (_Float16)x0.x; a[1] = (_Float16)x0.y;
      a[2] = (_Float16)x0.z; a[3] = (_Float16)x0.w;
      a[4] = (_Float16)x1.x; a[5] = (_Float16)x1.y;
      a[6] = (_Float16)x1.z; a[7] = (_Float16)x1.w;
#pragma unroll
      for (int nt = 0; nt < 4; ++nt)
        acc[nt] = __builtin_amdgcn_mfma_f32_16x16x32_f16(a, bf[k0i][nt],
                                                         acc[nt], 0, 0, 0);
    }
#pragma unroll
    for (int nt = 0; nt < 4; ++nt) {
      const int col = nt * 16 + rowi;
      const float bcol = bias[col] * bscale;
#pragma unroll
      for (int r = 0; r < 4; ++r) {
        const int row = r0 + kgrp * 4 + r;
        const float val = acc[nt][r] + bcol;
        hkv[(size_t)row * ROWH + uoff + col] =
            which ? f2bf(val) : f2h(val);
      }
    }
  } else {
    // tail rows (R%16 != 0 only): direct f32 dot, lane = column
    const float* __restrict__ W = which ? Wv : Wk;
    for (int r = r0; r < R; ++r) {
      const float* xr = X + (size_t)r * D_IN;
      float acc = bias[lane];
      for (int k = 0; k < D_IN; ++k)
        acc = fmaf(xr[k], W[(size_t)k * D_OUT + lane], acc);
      acc *= bscale;
      hkv[(size_t)r * ROWH + uoff + lane] = which ? f2bf(acc) : f2h(acc);
    }
  }
}

// ---------------------------------------------------------------------------
// Kernel B: CSR row pointers from sorted dst. row_ptr[i] = lower_bound(dst, i)
// ---------------------------------------------------------------------------
__global__ void rowptr_kernel(const int* __restrict__ dst, int E, int N,
                              int* __restrict__ row_ptr) {
  int i = blockIdx.x * blockDim.x + threadIdx.x;
  if (i > N) return;
  int lo = 0, hi = E;
  while (lo < hi) {
    int mid = (lo + hi) >> 1;
    if (dst[mid] < i) lo = mid + 1; else hi = mid;
  }
  row_ptr[i] = lo;
}

// ---------------------------------------------------------------------------
// sum over each 16-lane row via DPP rotate-adds (pure VALU).
// ---------------------------------------------------------------------------
__device__ __forceinline__ float rowsum16(float p) {
  union { float f; int i; } u, v;
  u.f = p;
  v.i = __builtin_amdgcn_update_dpp(0, u.i, 0x121, 0xF, 0xF, true);  // row_ror:1
  u.f += v.f;
  v.i = __builtin_amdgcn_update_dpp(0, u.i, 0x122, 0xF, 0xF, true);  // row_ror:2
  u.f += v.f;
  v.i = __builtin_amdgcn_update_dpp(0, u.i, 0x124, 0xF, 0xF, true);  // row_ror:4
  u.f += v.f;
  v.i = __builtin_amdgcn_update_dpp(0, u.i, 0x128, 0xF, 0xF, true);  // row_ror:8
  u.f += v.f;
  return u.f;
}

// online-softmax state, exp2 domain (hk pre-scaled so dot is log2-weighted)
struct SMState { float m, l; float4 a; };

// branchy update: common path = 1 exp2 + 5 fma; rescale only on new max
// (pl is uniform across the 16-lane group -> clean exec-mask branch)
__device__ __forceinline__ void sm_update(SMState& st, float pl,
                                          const uint2& vu) {
  if (pl > st.m) {
    const float sc = exp2f(st.m - pl);  // first edge: exp2(-inf) = 0
    st.l *= sc;
    st.a.x *= sc; st.a.y *= sc; st.a.z *= sc; st.a.w *= sc;
    st.m = pl;
  }
  const float a = exp2f(pl - st.m);
  const float4 vs = unpack_bf4(vu);
  st.l += a;
  st.a.x = fmaf(a, vs.x, st.a.x);
  st.a.y = fmaf(a, vs.y, st.a.y);
  st.a.z = fmaf(a, vs.z, st.a.z);
  st.a.w = fmaf(a, vs.w, st.a.w);
}

__device__ __forceinline__ void sm_merge(SMState& d, const SMState& s) {
  const float mn = fmaxf(d.m, s.m);
  const float s1 = exp2f(d.m - mn);
  const float s2 = exp2f(s.m - mn);
  d.l = d.l * s1 + s.l * s2;
  d.a.x = d.a.x * s1 + s.a.x * s2;
  d.a.y = d.a.y * s1 + s.a.y * s2;
  d.a.z = d.a.z * s1 + s.a.z * s2;
  d.a.w = d.a.w * s1 + s.a.w * s2;
  d.m = mn;
}

__device__ __forceinline__ void sm_merge_xor(SMState& d, int off) {
  SMState s;
  s.m = __shfl_xor(d.m, off, 64);
  s.l = __shfl_xor(d.l, off, 64);
  s.a.x = __shfl_xor(d.a.x, off, 64);
  s.a.y = __shfl_xor(d.a.y, off, 64);
  s.a.z = __shfl_xor(d.a.z, off, 64);
  s.a.w = __shfl_xor(d.a.w, off, 64);
  sm_merge(d, s);
}

// ---------------------------------------------------------------------------
// Kernel C: per-node segmented online-softmax aggregation, BOTH batches per
// wave. 4 groups of 16 lanes; per group 2 ILP states x 2 batches. Per
// iteration all 8 row-loads are issued BEFORE any (branchy) compute.
// hk fp16 (pre-scaled to exp2 domain) via v_dot2_f32_f16; hv bf16.
// [R11-exact: measured 68.5 us, VALUBusy 86%, 3.08 TB/s L2-miss BW]
// ---------------------------------------------------------------------------
__global__ __launch_bounds__(256) void aggregate_kernel(
    const unsigned short* __restrict__ hkv, const int* __restrict__ src,
    const int* __restrict__ row_ptr, float* __restrict__ out, int N) {
  const int node = blockIdx.x * 4 + (threadIdx.x >> 6);
  const int lane = threadIdx.x & 63;
  if (node >= N) return;
  const unsigned short* hb0 = hkv;
  const unsigned short* hb1 = hkv + (size_t)N * ROWH;

  const int li = lane & 15;  // dim-quad index (uint2 granule)
  const int g = lane >> 4;   // edge group

  const uint2 kd0 = reinterpret_cast<const uint2*>(hb0 + (size_t)node * ROWH)[li];
  const uint2 kd1 = reinterpret_cast<const uint2*>(hb1 + (size_t)node * ROWH)[li];
  const int e0 = row_ptr[node];
  const int e1 = row_ptr[node + 1];

  SMState A0 = {-FLT_MAX, 0.f, {0.f, 0.f, 0.f, 0.f}};
  SMState B0 = A0, A1 = A0, B1 = A0;

  int e = e0 + g;
  for (; e + 4 < e1; e += 8) {
    const int sA = src[e];
    const int sB = src[e + 4];
    const uint2* rA0 = reinterpret_cast<const uint2*>(hb0 + (size_t)sA * ROWH);
    const uint2* rA1 = reinterpret_cast<const uint2*>(hb1 + (size_t)sA * ROWH);
    const uint2* rB0 = reinterpret_cast<const uint2*>(hb0 + (size_t)sB * ROWH);
    const uint2* rB1 = reinterpret_cast<const uint2*>(hb1 + (size_t)sB * ROWH);
    const uint2 kA0 = rA0[li], vA0 = rA0[16 + li];
    const uint2 kA1 = rA1[li], vA1 = rA1[16 + li];
    const uint2 kB0 = rB0[li], vB0 = rB0[16 + li];
    const uint2 kB1 = rB1[li], vB1 = rB1[16 + li];

    const float plA0 = rowsum16(hdot4(kA0, kd0));
    const float plA1 = rowsum16(hdot4(kA1, kd1));
    const float plB0 = rowsum16(hdot4(kB0, kd0));
    const float plB1 = rowsum16(hdot4(kB1, kd1));

    sm_update(A0, plA0, vA0);
    sm_update(A1, plA1, vA1);
    sm_update(B0, plB0, vB0);
    sm_update(B1, plB1, vB1);
  }
  if (e < e1) {
    const int sA = src[e];
    const uint2* rA0 = reinterpret_cast<const uint2*>(hb0 + (size_t)sA * ROWH);
    const uint2* rA1 = reinterpret_cast<const uint2*>(hb1 + (size_t)sA * ROWH);
    const uint2 kA0 = rA0[li], vA0 = rA0[16 + li];
    const uint2 kA1 = rA1[li], vA1 = rA1[16 + li];
    const float plA0 = rowsum16(hdot4(kA0, kd0));
    const float plA1 = rowsum16(hdot4(kA1, kd1));
    sm_update(A0, plA0, vA0);
    sm_update(A1, plA1, vA1);
  }

  sm_merge(A0, B0);
  sm_merge(A1, B1);
  sm_merge_xor(A0, 16); sm_merge_xor(A0, 32);
  sm_merge_xor(A1, 16); sm_merge_xor(A1, 32);

  if (lane < 16) {
#pragma unroll
    for (int b = 0; b < 2; ++b) {
      const SMState& S = b ? A1 : A0;
      const float denom = (S.l == 0.f) ? 1.f : S.l;
      float4 o;
      o.x = S.a.x / denom; o.y = S.a.y / denom;
      o.z = S.a.z / denom; o.w = S.a.w / denom;
      o.x = (o.x >= 0.f) ? o.x : NEG_SLOPE * o.x;
      o.y = (o.y >= 0.f) ? o.y : NEG_SLOPE * o.y;
      o.z = (o.z >= 0.f) ? o.z : NEG_SLOPE * o.z;
      o.w = (o.w >= 0.f) ? o.w : NEG_SLOPE * o.w;
      *reinterpret_cast<float4*>(out + ((size_t)b * N + node) * D_OUT + 4 * lane) = o;
    }
  }
}

// ---------------------------------------------------------------------------
extern "C" void kernel_launch(void* const* d_in, const int* in_sizes, int n_in,
                              void* d_out, int out_size, void* d_ws,
                              size_t ws_size, hipStream_t stream) {
  const float* X_key   = (const float*)d_in[0];
  const float* X_value = (const float*)d_in[1];
  const float* Wk      = (const float*)d_in[2];
  const float* bk      = (const float*)d_in[3];
  const float* Wv      = (const float*)d_in[4];
  const float* bv      = (const float*)d_in[5];
  const int*   src     = (const int*)d_in[6];
  const int*   dst     = (const int*)d_in[7];
  float* out = (float*)d_out;

  const int B = 2;
  const int R = in_sizes[0] / D_IN;  // B*N rows
  const int N = R / B;
  const int E = in_sizes[6];

  // workspace: bfrag 32KB (16B-aligned) | hkv ushort[R][128] | row_ptr
  _Float16* bfrag = (_Float16*)d_ws;
  unsigned short* hkv = (unsigned short*)((char*)d_ws + 32768);
  int* row_ptr = (int*)(hkv + (size_t)R * ROWH);

  const int blocksB = (N + 1 + 255) / 256;
  hipLaunchKernelGGL(rowptr_kernel, dim3(blocksB), dim3(256), 0, stream,
                     dst, E, N, row_ptr);
  hipLaunchKernelGGL(bfrag_kernel, dim3(8), dim3(256), 0, stream,
                     Wk, Wv, bfrag);
  const int wavesPerMat = (R + 15) / 16;
  const int nblk = (wavesPerMat + 3) / 4;
  hipLaunchKernelGGL(linear_mfma_kernel, dim3(2 * nblk), dim3(256), 0, stream,
                     X_key, X_value, Wk, bk, Wv, bv, bfrag, hkv, R, nblk);
  const int blocksC = (N + 3) / 4;  // one wave per node, both batches
  hipLaunchKernelGGL(aggregate_kernel, dim3(blocksC), dim3(256), 0, stream,
                     hkv, src, row_ptr, out, N);
}